// Round 2
// baseline (276.395 us; speedup 1.0000x reference)
//
#include <hip/hip_runtime.h>
#include <math.h>

// PCEN: x[B=64, C=128, T=4000] fp32.
// smooth[0]=x[0]; smooth[t]=(1-s)*smooth[t-1]+s*x[t], s=0.025
// out = sqrt(x/(smooth+1e-6)^0.98 + 2) - sqrt(2)
//
// One WAVE per channel (no LDS, no __syncthreads). Each lane owns 64
// contiguous elements (16 float4). Constant-coefficient recurrence ->
// per-lane affine map (A=0.975^64, B=scan with zero init), 6-step shuffle
// scan composes maps across lanes, then replay from registers with the true
// init + hardware-transcendental epilogue (v_log/v_exp/v_rsq).

constexpr int   TLEN = 4000;
constexpr int   NF4  = 1000;          // float4s per channel
constexpr float S_C  = 0.025f;
constexpr float A_1  = 1.0f - S_C;    // 0.975

constexpr float fpow(float b, int n) {
    float r = 1.0f;
    for (int i = 0; i < n; ++i) r *= b;
    return r;
}
constexpr float A_2  = fpow(A_1, 2);
constexpr float A_3  = fpow(A_1, 3);
constexpr float A_4  = fpow(A_1, 4);
constexpr float A_64 = fpow(A_1, 64);

constexpr float ALPHA = 0.98f;
constexpr float EPS_C = 1e-6f;
constexpr float SQRT2 = 1.41421356237309515f;

__device__ __forceinline__ float pcen_elem(float x, float sm) {
    float t     = sm + EPS_C;
    float p     = exp2f(-ALPHA * __log2f(t));   // t^-alpha  (v_exp_f32, v_log_f32)
    float y     = fmaf(x, p, 2.0f);             // x/t^alpha + 2   (>= 2, rsq safe)
    return y * __frsqrt_rn(y) - SQRT2;          // sqrt(y) - sqrt(2)
}

__global__ __launch_bounds__(256) void pcen_kernel(const float* __restrict__ x,
                                                   float* __restrict__ out) {
    const int tid  = threadIdx.x;
    const int lane = tid & 63;
    const int wv   = tid >> 6;
    const int ch   = blockIdx.x * 4 + wv;       // one wave per channel

    const size_t  base = (size_t)ch * TLEN;
    const float4* __restrict__ x4 = (const float4*)(x + base);
    float4*       __restrict__ o4 = (float4*)(out + base);

    // ---- load 16 float4 (lane's 64 contiguous elements); tail lanes zero ----
    float4 v[16];
#pragma unroll
    for (int q = 0; q < 16; ++q) {
        int f4 = lane * 16 + q;
        if (f4 < NF4) v[q] = x4[f4];
        else          v[q] = make_float4(0.f, 0.f, 0.f, 0.f);
    }

    // ---- pass 1: per-lane affine B (zero init), grouped per float4 ----
    // group value: w = A3*s*x0 + s*(A2*x1 + A1*x2 + x3); sm = A4*sm + w
    // global element 0 (lane0,q0,.x): coefficient 1 instead of s (smooth[0]=x[0])
    float sm = 0.0f;
#pragma unroll
    for (int q = 0; q < 16; ++q) {
        float4 r  = v[q];
        float  b0 = (q == 0 && lane == 0) ? r.x : S_C * r.x;
        float  w  = fmaf(A_3, b0, S_C * fmaf(A_2, r.y, fmaf(A_1, r.z, r.w)));
        sm = fmaf(A_4, sm, w);
    }

    // ---- 6-step wave-inclusive scan over affine maps (A,B) ----
    float A = A_64;
    float B = sm;
#pragma unroll
    for (int d = 1; d < 64; d <<= 1) {
        float Ap = __shfl_up(A, d);
        float Bp = __shfl_up(B, d);
        if (lane >= d) {
            B = fmaf(A, Bp, B);
            A = A * Ap;
        }
    }
    // exclusive prefix value entering this lane (global init is 0)
    float init = __shfl_up(B, 1);
    if (lane == 0) init = 0.0f;

    // ---- pass 2: replay from registers + epilogue + store ----
    sm = init;
#pragma unroll
    for (int q = 0; q < 16; ++q) {
        float4 r  = v[q];
        float  b0 = (q == 0 && lane == 0) ? r.x : S_C * r.x;
        float  s0 = fmaf(A_1, sm, b0);
        float  s1 = fmaf(A_1, s0, S_C * r.y);
        float  s2 = fmaf(A_1, s1, S_C * r.z);
        float  s3 = fmaf(A_1, s2, S_C * r.w);
        sm = s3;

        float4 o;
        o.x = pcen_elem(r.x, s0);
        o.y = pcen_elem(r.y, s1);
        o.z = pcen_elem(r.z, s2);
        o.w = pcen_elem(r.w, s3);

        int f4 = lane * 16 + q;
        if (f4 < NF4) o4[f4] = o;
    }
}

extern "C" void kernel_launch(void* const* d_in, const int* in_sizes, int n_in,
                              void* d_out, int out_size, void* d_ws, size_t ws_size,
                              hipStream_t stream) {
    const float* x   = (const float*)d_in[0];
    float*       out = (float*)d_out;
    const int nch    = in_sizes[0] / TLEN;   // 8192 channels
    pcen_kernel<<<nch / 4, 256, 0, stream>>>(x, out);
}

// Round 3
// 215.461 us; speedup vs baseline: 1.2828x; 1.2828x over previous
//
#include <hip/hip_runtime.h>
#include <math.h>

// PCEN: x[B=64, C=128, T=4000] fp32.
// smooth[0]=x[0]; smooth[t]=(1-s)*smooth[t-1]+s*x[t], s=0.025
// out = sqrt(x/(smooth+1e-6)^0.98 + 2) - sqrt(2)
//
// One block (256 threads) per channel, COALESCED layout: thread t owns the
// float4s {t, t+256, t+512, t+768} -> every global load/store instruction is
// lane-dense (lane i touches consecutive 16 B), the m13 6.3 TB/s pattern.
// Scan order over 1024 mini-chunks m = 256*k + t; each mini-chunk (4 elems)
// is an affine map (A=0.975^4, B). 4 interleaved wave-shuffle scans (ILP),
// 16-entry LDS table of wave totals for the cross-wave/cross-segment prefix,
// then replay + hardware-transcendental epilogue (v_log/v_exp/v_rsq).

constexpr int   TLEN = 4000;
constexpr int   NF4  = 1000;
constexpr int   NTH  = 256;
constexpr float S_C  = 0.025f;
constexpr float A_1  = 1.0f - S_C;

constexpr float fpow(float b, int n) {
    float r = 1.0f;
    for (int i = 0; i < n; ++i) r *= b;
    return r;
}
constexpr float A_2 = fpow(A_1, 2);
constexpr float A_3 = fpow(A_1, 3);
constexpr float A_4 = fpow(A_1, 4);

constexpr float ALPHA = 0.98f;
constexpr float EPS_C = 1e-6f;
constexpr float SQRT2 = 1.41421356237309515f;

__device__ __forceinline__ float pcen_elem(float x, float sm) {
    float t = sm + EPS_C;
    float p = exp2f(-ALPHA * __log2f(t));   // t^-alpha   (v_exp_f32 + v_log_f32)
    float y = fmaf(x, p, 2.0f);             // >= 2, rsq-safe
    return y * __frsqrt_rn(y) - SQRT2;      // sqrt(y) - sqrt(2)
}

__global__ __launch_bounds__(NTH) void pcen_kernel(const float* __restrict__ x,
                                                   float* __restrict__ out) {
    const int    tid  = threadIdx.x;
    const int    lane = tid & 63;
    const int    wv   = tid >> 6;
    const size_t base = (size_t)blockIdx.x * TLEN;

    const float4* __restrict__ x4 = (const float4*)(x + base);
    float4*       __restrict__ o4 = (float4*)(out + base);

    // ---- coalesced load: 4 lane-dense float4 loads ----
    float4 v[4];
    bool   act[4];
#pragma unroll
    for (int k = 0; k < 4; ++k) {
        int f4 = tid + NTH * k;
        act[k] = (f4 < NF4);
        v[k]   = act[k] ? x4[f4] : make_float4(0.f, 0.f, 0.f, 0.f);
    }

    // ---- per-mini-chunk affine map (zero-init value B, coefficient A) ----
    // chunk value from init sm: A_4*sm + w,  w = A3*b0 + s*(A2*x1 + A1*x2 + x3)
    float A[4], B[4];
#pragma unroll
    for (int k = 0; k < 4; ++k) {
        float4 r  = v[k];
        float  b0 = (tid == 0 && k == 0) ? r.x : S_C * r.x;  // smooth[0]=x[0]
        float  w  = fmaf(A_3, b0, S_C * fmaf(A_2, r.y, fmaf(A_1, r.z, r.w)));
        A[k] = act[k] ? A_4 : 1.0f;   // inactive trailing chunks = identity
        B[k] = act[k] ? w   : 0.0f;
    }

    // ---- 4 interleaved inclusive wave scans over (A,B) ----
#pragma unroll
    for (int d = 1; d < 64; d <<= 1) {
        float Ap[4], Bp[4];
#pragma unroll
        for (int k = 0; k < 4; ++k) {
            Ap[k] = __shfl_up(A[k], d);
            Bp[k] = __shfl_up(B[k], d);
        }
        if (lane >= d) {
#pragma unroll
            for (int k = 0; k < 4; ++k) {
                B[k] = fmaf(A[k], Bp[k], B[k]);
                A[k] = A[k] * Ap[k];
            }
        }
    }

    // ---- wave totals -> LDS (16 (A,B) pairs, ordered m-major: seg k, wave w) ----
    __shared__ float sA[4][4], sB[4][4];
    if (lane == 63) {
#pragma unroll
        for (int k = 0; k < 4; ++k) { sA[k][wv] = A[k]; sB[k][wv] = B[k]; }
    }
    __syncthreads();

    // ---- per-(wv,k) entering prefix: compose wave totals with index < 4k+wv ----
    float E[4];
#pragma unroll
    for (int k = 0; k < 4; ++k) {
        int   lim = 4 * k + wv;
        float e   = 0.0f;
        for (int m = 0; m < 15; ++m) {           // m = 4*kk + w
            if (m < lim) e = fmaf(sA[m >> 2][m & 3], e, sB[m >> 2][m & 3]);
        }
        E[k] = e;
    }

    // ---- thread-exclusive prefix within wave, replay, epilogue, dense store ----
#pragma unroll
    for (int k = 0; k < 4; ++k) {
        float Ai = __shfl_up(A[k], 1);
        float Bi = __shfl_up(B[k], 1);
        if (lane == 0) { Ai = 1.0f; Bi = 0.0f; }
        float sm = fmaf(Ai, E[k], Bi);           // smoothed value entering chunk

        float4 r  = v[k];
        float  b0 = (tid == 0 && k == 0) ? r.x : S_C * r.x;
        float  s0 = fmaf(A_1, sm, b0);
        float  s1 = fmaf(A_1, s0, S_C * r.y);
        float  s2 = fmaf(A_1, s1, S_C * r.z);
        float  s3 = fmaf(A_1, s2, S_C * r.w);

        float4 o;
        o.x = pcen_elem(r.x, s0);
        o.y = pcen_elem(r.y, s1);
        o.z = pcen_elem(r.z, s2);
        o.w = pcen_elem(r.w, s3);

        int f4 = tid + NTH * k;
        if (act[k]) o4[f4] = o;
    }
}

extern "C" void kernel_launch(void* const* d_in, const int* in_sizes, int n_in,
                              void* d_out, int out_size, void* d_ws, size_t ws_size,
                              hipStream_t stream) {
    const float* x   = (const float*)d_in[0];
    float*       out = (float*)d_out;
    const int nch    = in_sizes[0] / TLEN;   // 8192 channels
    pcen_kernel<<<nch, NTH, 0, stream>>>(x, out);
}